// Round 1
// baseline (446.697 us; speedup 1.0000x reference)
//
#include <hip/hip_runtime.h>
#include <hip/hip_bf16.h>

#define TILE_M 128
#define TILE_N 128
#define TILE_K 64
#define THREADS 256
#define K_DIM 4096
#define N_DIM 4096
#define M_DIM 8192
#define PW_COLS 1024  // K_DIM/4

typedef __attribute__((ext_vector_type(4))) float f32x4;
typedef __attribute__((ext_vector_type(8))) short bf16x8;

__device__ __forceinline__ unsigned short f2bf(float f) {
    unsigned int u = __float_as_uint(f);
    u += 0x7FFF + ((u >> 16) & 1);   // round-to-nearest-even
    return (unsigned short)(u >> 16);
}

// ternary code {0,1,2,3} -> bf16 bits of {-1,0,1,2}
__device__ __forceinline__ unsigned short wlut(int tt) {
    return (unsigned short)(0x40003F800000BF80ULL >> (tt << 4));
}

__global__ __launch_bounds__(THREADS)
void ternary_mm_kernel(const float* __restrict__ x,
                       const int* __restrict__ pw,
                       const float* __restrict__ scale,
                       const float* __restrict__ bias,
                       float* __restrict__ out)
{
    // bf16 tiles, XOR-swizzled byte addressing (row stride 128B)
    __shared__ unsigned char As[TILE_M * TILE_K * 2];
    __shared__ unsigned char Ws[TILE_N * TILE_K * 2];

    const int t    = threadIdx.x;
    const int lane = t & 63;
    const int wave = t >> 6;
    const int wr = wave >> 1;        // 0..1  (M half)
    const int wc = wave & 1;         // 0..1  (N half)
    const int lr = lane & 15;
    const int lk = lane >> 4;        // 0..3

    const int n0 = blockIdx.x * TILE_N;
    const int m0 = blockIdx.y * TILE_M;

    f32x4 acc[4][4];
#pragma unroll
    for (int m = 0; m < 4; ++m)
#pragma unroll
        for (int n = 0; n < 4; ++n)
            acc[m][n] = (f32x4){0.f, 0.f, 0.f, 0.f};

    for (int kt = 0; kt < K_DIM; kt += TILE_K) {
        // ---- stage A: 128 rows x 64 cols fp32 -> bf16 ----
#pragma unroll
        for (int p = 0; p < 8; ++p) {
            int idx = p * THREADS + t;           // 0..2047
            int row = idx >> 4;                  // 0..127
            int c4  = idx & 15;                  // float4 index within row
            float4 v = *(const float4*)(x + (size_t)(m0 + row) * K_DIM + kt + c4 * 4);
            ushort4 o;
            o.x = f2bf(v.x); o.y = f2bf(v.y); o.z = f2bf(v.z); o.w = f2bf(v.w);
            int off = (row * 128 + c4 * 8) ^ ((row & 7) << 4);
            *(ushort4*)(As + off) = o;
        }
        // ---- stage W: 128 rows x 16 packed int32 -> 64 bf16 per row ----
#pragma unroll
        for (int p = 0; p < 2; ++p) {
            int idx = p * THREADS + t;           // 0..511
            int row = idx >> 2;                  // 0..127
            int q   = idx & 3;                   // int4 index within row
            int4 v = *(const int4*)(pw + (size_t)(n0 + row) * PW_COLS + (kt >> 2) + q * 4);
            int base = row * 128 + q * 32;
            int xr = (row & 7) << 4;
            int pv[4] = {v.x, v.y, v.z, v.w};
#pragma unroll
            for (int j = 0; j < 4; ++j) {
                ushort4 o;
                o.x = wlut( pv[j]       & 3);
                o.y = wlut((pv[j] >> 2) & 3);
                o.z = wlut((pv[j] >> 4) & 3);
                o.w = wlut((pv[j] >> 6) & 3);
                *(ushort4*)(Ws + ((base + j * 8) ^ xr)) = o;
            }
        }
        __syncthreads();

        // ---- MFMA over the K-tile (2 k-steps of 32) ----
#pragma unroll
        for (int kk = 0; kk < 2; ++kk) {
            const int cb = kk * 64 + lk * 16;    // col byte offset
            bf16x8 af[4], bw[4];
#pragma unroll
            for (int m = 0; m < 4; ++m) {
                int row = wr * 64 + m * 16 + lr;
                af[m] = *(const bf16x8*)(As + ((row * 128 + cb) ^ ((lr & 7) << 4)));
            }
#pragma unroll
            for (int n = 0; n < 4; ++n) {
                int row = wc * 64 + n * 16 + lr;
                bw[n] = *(const bf16x8*)(Ws + ((row * 128 + cb) ^ ((lr & 7) << 4)));
            }
#pragma unroll
            for (int m = 0; m < 4; ++m)
#pragma unroll
                for (int n = 0; n < 4; ++n)
                    acc[m][n] = __builtin_amdgcn_mfma_f32_16x16x32_bf16(
                        af[m], bw[n], acc[m][n], 0, 0, 0);
        }
        __syncthreads();
    }

    // ---- epilogue: scale/bias/clip, fp32 store ----
#pragma unroll
    for (int n = 0; n < 4; ++n) {
        int gcol = n0 + wc * 64 + n * 16 + lr;
        float s = scale[gcol];
        float b = bias[gcol];
#pragma unroll
        for (int m = 0; m < 4; ++m) {
            int growb = m0 + wr * 64 + m * 16 + lk * 4;
#pragma unroll
            for (int r = 0; r < 4; ++r) {
                float v = acc[m][n][r] * s + b;
                v = fminf(fmaxf(v, -100.0f), 100.0f);
                out[(size_t)(growb + r) * N_DIM + gcol] = v;
            }
        }
    }
}

extern "C" void kernel_launch(void* const* d_in, const int* in_sizes, int n_in,
                              void* d_out, int out_size, void* d_ws, size_t ws_size,
                              hipStream_t stream) {
    const float* x     = (const float*)d_in[0];
    const int*   pw    = (const int*)d_in[1];
    const float* scale = (const float*)d_in[2];
    const float* bias  = (const float*)d_in[3];
    float* out = (float*)d_out;

    dim3 grid(N_DIM / TILE_N, M_DIM / TILE_M);   // (32, 64)
    ternary_mm_kernel<<<grid, THREADS, 0, stream>>>(x, pw, scale, bias, out);
}

// Round 2
// 434.216 us; speedup vs baseline: 1.0287x; 1.0287x over previous
//
#include <hip/hip_runtime.h>
#include <hip/hip_bf16.h>

#define K_DIM 4096
#define N_DIM 4096
#define M_DIM 8192
#define PW_COLS 1024  // K_DIM/4

typedef __attribute__((ext_vector_type(4))) float f32x4;
typedef __attribute__((ext_vector_type(8))) short bf16x8;
typedef __attribute__((address_space(3))) void lds_void_t;
typedef __attribute__((address_space(1))) const void glb_void_t;

__device__ __forceinline__ unsigned short f2bf(float f) {
    unsigned int u = __float_as_uint(f);
    u += 0x7FFF + ((u >> 16) & 1);   // round-to-nearest-even
    return (unsigned short)(u >> 16);
}

// ternary code {0,1,2,3} -> bf16 bits of {-1,0,1,2}
__device__ __forceinline__ unsigned short wlut(int tt) {
    return (unsigned short)(0x40003F800000BF80ULL >> (tt << 4));
}

// ---------------- pre-pass 1: x fp32 -> bf16 ----------------
__global__ __launch_bounds__(256)
void convert_x_kernel(const float* __restrict__ x, unsigned short* __restrict__ xb, int n8)
{
    int stride = gridDim.x * blockDim.x;
    for (int i = blockIdx.x * blockDim.x + threadIdx.x; i < n8; i += stride) {
        float4 v0 = *(const float4*)(x + (size_t)i * 8);
        float4 v1 = *(const float4*)(x + (size_t)i * 8 + 4);
        ushort4 o0, o1;
        o0.x = f2bf(v0.x); o0.y = f2bf(v0.y); o0.z = f2bf(v0.z); o0.w = f2bf(v0.w);
        o1.x = f2bf(v1.x); o1.y = f2bf(v1.y); o1.z = f2bf(v1.z); o1.w = f2bf(v1.w);
        *(ushort4*)(xb + (size_t)i * 8) = o0;
        *(ushort4*)(xb + (size_t)i * 8 + 4) = o1;
    }
}

// ---------------- pre-pass 2: pw -> bf16 W [N][K] ----------------
__global__ __launch_bounds__(256)
void unpack_w_kernel(const int* __restrict__ pw, unsigned short* __restrict__ wb, int n2)
{
    int stride = gridDim.x * blockDim.x;
    for (int i = blockIdx.x * blockDim.x + threadIdx.x; i < n2; i += stride) {
        int2 p = *(const int2*)(pw + (size_t)i * 2);
        ushort4 a, b;
        a.x = wlut( p.x       & 3);
        a.y = wlut((p.x >> 2) & 3);
        a.z = wlut((p.x >> 4) & 3);
        a.w = wlut((p.x >> 6) & 3);
        b.x = wlut( p.y       & 3);
        b.y = wlut((p.y >> 2) & 3);
        b.z = wlut((p.y >> 4) & 3);
        b.w = wlut((p.y >> 6) & 3);
        *(ushort4*)(wb + (size_t)i * 8) = a;
        *(ushort4*)(wb + (size_t)i * 8 + 4) = b;
    }
}

// ---------------- main GEMM: bf16 B^T, m97 structure ----------------
#define BM 128
#define BN 128
#define BK 64

__global__ __launch_bounds__(256)
void gemm_bt_kernel(const unsigned short* __restrict__ A,   // [M][K] bf16
                    const unsigned short* __restrict__ B,   // [N][K] bf16
                    const float* __restrict__ scale,
                    const float* __restrict__ bias,
                    float* __restrict__ out)
{
    __shared__ unsigned short As[BM * BK];   // 16 KB, row-major stride 64
    __shared__ unsigned short Bs[BN * BK];   // 16 KB

    const int t    = threadIdx.x;
    const int lane = t & 63;
    const int wave = t >> 6;
    const int wr = wave >> 1;        // 0..1  (M half)
    const int wc = wave & 1;         // 0..1  (N half)
    const int lr = lane & 15;
    const int lk = lane >> 4;        // 0..3

    // XCD-aware swizzle: 2048 blocks, 8 XCDs -> contiguous 256-block chunks
    int wg = (blockIdx.x & 7) * 256 + (blockIdx.x >> 3);
    const int m0 = (wg >> 5) * BM;   // 64 m-blocks
    const int n0 = (wg & 31) * BN;   // 32 n-blocks

    f32x4 acc[4][4];
#pragma unroll
    for (int m = 0; m < 4; ++m)
#pragma unroll
        for (int n = 0; n < 4; ++n)
            acc[m][n] = (f32x4){0.f, 0.f, 0.f, 0.f};

    const int lrow8 = lane >> 3;     // 0..7
    const int lcol8 = (lane & 7) * 8;

    for (int kt = 0; kt < K_DIM; kt += BK) {
        // stage A,B via async global->LDS, 16B/lane, wave-uniform LDS base
#pragma unroll
        for (int j = 0; j < 4; ++j) {
            int c = wave * 4 + j;                     // chunk 0..15 (8 rows each)
            const unsigned short* srcA =
                A + (size_t)(m0 + c * 8 + lrow8) * K_DIM + kt + lcol8;
            __builtin_amdgcn_global_load_lds((glb_void_t*)srcA,
                (lds_void_t*)(void*)((char*)As + c * 1024), 16, 0, 0);
            const unsigned short* srcB =
                B + (size_t)(n0 + c * 8 + lrow8) * K_DIM + kt + lcol8;
            __builtin_amdgcn_global_load_lds((glb_void_t*)srcB,
                (lds_void_t*)(void*)((char*)Bs + c * 1024), 16, 0, 0);
        }
        __syncthreads();   // drains vmcnt: LDS tiles ready

#pragma unroll
        for (int kk = 0; kk < 2; ++kk) {
            const int cofs = kk * 32 + lk * 8;
            bf16x8 af[4], bw[4];
#pragma unroll
            for (int m = 0; m < 4; ++m)
                af[m] = *(const bf16x8*)&As[(wr * 64 + m * 16 + lr) * BK + cofs];
#pragma unroll
            for (int n = 0; n < 4; ++n)
                bw[n] = *(const bf16x8*)&Bs[(wc * 64 + n * 16 + lr) * BK + cofs];
#pragma unroll
            for (int m = 0; m < 4; ++m)
#pragma unroll
                for (int n = 0; n < 4; ++n)
                    acc[m][n] = __builtin_amdgcn_mfma_f32_16x16x32_bf16(
                        af[m], bw[n], acc[m][n], 0, 0, 0);
        }
        __syncthreads();   // all reads done before next stage overwrites
    }

    // epilogue: scale/bias/clip, fp32 store
#pragma unroll
    for (int n = 0; n < 4; ++n) {
        int gcol = n0 + wc * 64 + n * 16 + lr;
        float s = scale[gcol];
        float b = bias[gcol];
#pragma unroll
        for (int m = 0; m < 4; ++m) {
            int growb = m0 + wr * 64 + m * 16 + lk * 4;
#pragma unroll
            for (int r = 0; r < 4; ++r) {
                float v = acc[m][n][r] * s + b;
                v = fminf(fmaxf(v, -100.0f), 100.0f);
                out[(size_t)(growb + r) * N_DIM + gcol] = v;
            }
        }
    }
}

// ---------------- fallback: round-1 fused kernel ----------------
__global__ __launch_bounds__(256)
void ternary_mm_fused(const float* __restrict__ x,
                      const int* __restrict__ pw,
                      const float* __restrict__ scale,
                      const float* __restrict__ bias,
                      float* __restrict__ out)
{
    __shared__ unsigned char As[BM * BK * 2];
    __shared__ unsigned char Ws[BN * BK * 2];

    const int t    = threadIdx.x;
    const int lane = t & 63;
    const int wave = t >> 6;
    const int wr = wave >> 1;
    const int wc = wave & 1;
    const int lr = lane & 15;
    const int lk = lane >> 4;

    const int n0 = blockIdx.x * BN;
    const int m0 = blockIdx.y * BM;

    f32x4 acc[4][4];
#pragma unroll
    for (int m = 0; m < 4; ++m)
#pragma unroll
        for (int n = 0; n < 4; ++n)
            acc[m][n] = (f32x4){0.f, 0.f, 0.f, 0.f};

    for (int kt = 0; kt < K_DIM; kt += BK) {
#pragma unroll
        for (int p = 0; p < 8; ++p) {
            int idx = p * 256 + t;
            int row = idx >> 4;
            int c4  = idx & 15;
            float4 v = *(const float4*)(x + (size_t)(m0 + row) * K_DIM + kt + c4 * 4);
            ushort4 o;
            o.x = f2bf(v.x); o.y = f2bf(v.y); o.z = f2bf(v.z); o.w = f2bf(v.w);
            int off = (row * 128 + c4 * 8) ^ ((row & 7) << 4);
            *(ushort4*)(As + off) = o;
        }
#pragma unroll
        for (int p = 0; p < 2; ++p) {
            int idx = p * 256 + t;
            int row = idx >> 2;
            int q   = idx & 3;
            int4 v = *(const int4*)(pw + (size_t)(n0 + row) * PW_COLS + (kt >> 2) + q * 4);
            int base = row * 128 + q * 32;
            int xr = (row & 7) << 4;
            int pv[4] = {v.x, v.y, v.z, v.w};
#pragma unroll
            for (int j = 0; j < 4; ++j) {
                ushort4 o;
                o.x = wlut( pv[j]       & 3);
                o.y = wlut((pv[j] >> 2) & 3);
                o.z = wlut((pv[j] >> 4) & 3);
                o.w = wlut((pv[j] >> 6) & 3);
                *(ushort4*)(Ws + ((base + j * 8) ^ xr)) = o;
            }
        }
        __syncthreads();

#pragma unroll
        for (int kk = 0; kk < 2; ++kk) {
            const int cb = kk * 64 + lk * 16;
            bf16x8 af[4], bw[4];
#pragma unroll
            for (int m = 0; m < 4; ++m) {
                int row = wr * 64 + m * 16 + lr;
                af[m] = *(const bf16x8*)(As + ((row * 128 + cb) ^ ((lr & 7) << 4)));
            }
#pragma unroll
            for (int n = 0; n < 4; ++n) {
                int row = wc * 64 + n * 16 + lr;
                bw[n] = *(const bf16x8*)(Ws + ((row * 128 + cb) ^ ((lr & 7) << 4)));
            }
#pragma unroll
            for (int m = 0; m < 4; ++m)
#pragma unroll
                for (int n = 0; n < 4; ++n)
                    acc[m][n] = __builtin_amdgcn_mfma_f32_16x16x32_bf16(
                        af[m], bw[n], acc[m][n], 0, 0, 0);
        }
        __syncthreads();
    }

#pragma unroll
    for (int n = 0; n < 4; ++n) {
        int gcol = n0 + wc * 64 + n * 16 + lr;
        float s = scale[gcol];
        float b = bias[gcol];
#pragma unroll
        for (int m = 0; m < 4; ++m) {
            int growb = m0 + wr * 64 + m * 16 + lk * 4;
#pragma unroll
            for (int r = 0; r < 4; ++r) {
                float v = acc[m][n][r] * s + b;
                v = fminf(fmaxf(v, -100.0f), 100.0f);
                out[(size_t)(growb + r) * N_DIM + gcol] = v;
            }
        }
    }
}

extern "C" void kernel_launch(void* const* d_in, const int* in_sizes, int n_in,
                              void* d_out, int out_size, void* d_ws, size_t ws_size,
                              hipStream_t stream) {
    const float* x     = (const float*)d_in[0];
    const int*   pw    = (const int*)d_in[1];
    const float* scale = (const float*)d_in[2];
    const float* bias  = (const float*)d_in[3];
    float* out = (float*)d_out;

    const size_t xb_bytes = (size_t)M_DIM * K_DIM * 2;           // 67,108,864
    const size_t wb_bytes = (size_t)N_DIM * K_DIM * 2;           // 33,554,432
    if (ws_size >= xb_bytes + wb_bytes) {
        unsigned short* xb = (unsigned short*)d_ws;
        unsigned short* wb = (unsigned short*)((char*)d_ws + xb_bytes);

        int n8 = (M_DIM * K_DIM) / 8;     // 4,194,304 groups of 8 floats
        convert_x_kernel<<<2048, 256, 0, stream>>>(x, xb, n8);
        int n2 = (N_DIM * PW_COLS) / 2;   // 2,097,152 groups of 2 ints
        unpack_w_kernel<<<2048, 256, 0, stream>>>(pw, wb, n2);

        dim3 grid((M_DIM / BM) * (N_DIM / BN));   // 2048
        gemm_bt_kernel<<<grid, 256, 0, stream>>>(xb, wb, scale, bias, out);
    } else {
        dim3 grid(N_DIM / BN, M_DIM / BM);
        ternary_mm_fused<<<grid, 256, 0, stream>>>(x, pw, scale, bias, out);
    }
}

// Round 3
// 261.142 us; speedup vs baseline: 1.7105x; 1.6628x over previous
//
#include <hip/hip_runtime.h>
#include <hip/hip_bf16.h>

#define K_DIM 4096
#define N_DIM 4096
#define M_DIM 8192
#define PW_COLS 1024  // K_DIM/4

typedef __attribute__((ext_vector_type(4))) float f32x4;
typedef __attribute__((ext_vector_type(8))) short bf16x8;
typedef __attribute__((address_space(3))) void lds_void_t;
typedef __attribute__((address_space(1))) const void glb_void_t;

__device__ __forceinline__ unsigned short f2bf(float f) {
    unsigned int u = __float_as_uint(f);
    u += 0x7FFF + ((u >> 16) & 1);   // round-to-nearest-even
    return (unsigned short)(u >> 16);
}

// ternary code {0,1,2,3} -> bf16 bits of {-1,0,1,2}
__device__ __forceinline__ unsigned short wlut(int tt) {
    return (unsigned short)(0x40003F800000BF80ULL >> (tt << 4));
}

// ---------------- pre-pass 1: x fp32 -> bf16 ----------------
__global__ __launch_bounds__(256)
void convert_x_kernel(const float* __restrict__ x, unsigned short* __restrict__ xb, int n8)
{
    int stride = gridDim.x * blockDim.x;
    for (int i = blockIdx.x * blockDim.x + threadIdx.x; i < n8; i += stride) {
        float4 v0 = *(const float4*)(x + (size_t)i * 8);
        float4 v1 = *(const float4*)(x + (size_t)i * 8 + 4);
        ushort4 o0, o1;
        o0.x = f2bf(v0.x); o0.y = f2bf(v0.y); o0.z = f2bf(v0.z); o0.w = f2bf(v0.w);
        o1.x = f2bf(v1.x); o1.y = f2bf(v1.y); o1.z = f2bf(v1.z); o1.w = f2bf(v1.w);
        *(ushort4*)(xb + (size_t)i * 8) = o0;
        *(ushort4*)(xb + (size_t)i * 8 + 4) = o1;
    }
}

// ---------------- pre-pass 2: pw -> bf16 W [N][K] ----------------
__global__ __launch_bounds__(256)
void unpack_w_kernel(const int* __restrict__ pw, unsigned short* __restrict__ wb, int n2)
{
    int stride = gridDim.x * blockDim.x;
    for (int i = blockIdx.x * blockDim.x + threadIdx.x; i < n2; i += stride) {
        int2 p = *(const int2*)(pw + (size_t)i * 2);
        ushort4 a, b;
        a.x = wlut( p.x       & 3);
        a.y = wlut((p.x >> 2) & 3);
        a.z = wlut((p.x >> 4) & 3);
        a.w = wlut((p.x >> 6) & 3);
        b.x = wlut( p.y       & 3);
        b.y = wlut((p.y >> 2) & 3);
        b.z = wlut((p.y >> 4) & 3);
        b.w = wlut((p.y >> 6) & 3);
        *(ushort4*)(wb + (size_t)i * 8) = a;
        *(ushort4*)(wb + (size_t)i * 8 + 4) = b;
    }
}

// ---------------- main GEMM: 256x256 tile, 4-phase/tile, counted vmcnt ----------------
#define BM 256
#define BN 256
#define BK 64
#define GTHREADS 512
#define BUF_BYTES 65536   // A 32K + B 32K
#define B_TILE 32768
#define HALF 16384
#define NTILES 64         // K_DIM / BK

#define BARRIER() asm volatile("s_barrier" ::: "memory")

#define MM_Q(MH, NH) do { \
    __builtin_amdgcn_s_setprio(1); \
    _Pragma("unroll") \
    for (int im = 0; im < 4; ++im) { \
      _Pragma("unroll") \
      for (int jn = 0; jn < 2; ++jn) { \
        acc[MH][im][NH][jn] = __builtin_amdgcn_mfma_f32_16x16x32_bf16( \
            afr[im][0], bfr[NH][jn][0], acc[MH][im][NH][jn], 0, 0, 0); \
        acc[MH][im][NH][jn] = __builtin_amdgcn_mfma_f32_16x16x32_bf16( \
            afr[im][1], bfr[NH][jn][1], acc[MH][im][NH][jn], 0, 0, 0); \
      } \
    } \
    __builtin_amdgcn_s_setprio(0); \
} while (0)

__global__ __launch_bounds__(GTHREADS, 2)
void gemm_8phase(const unsigned short* __restrict__ A,   // [M][K] bf16
                 const unsigned short* __restrict__ B,   // [N][K] bf16
                 const float* __restrict__ scale,
                 const float* __restrict__ bias,
                 float* __restrict__ out)
{
    extern __shared__ __align__(16) char smem[];

    const int t    = threadIdx.x;
    const int lane = t & 63;
    const int wave = t >> 6;
    const int wm = wave >> 2;      // 0..1  (M group)
    const int wn = wave & 3;       // 0..3  (N group)
    const int lr = lane & 15;
    const int lk = lane >> 4;      // 0..3

    // bijective XCD swizzle: 512 blocks, 8 XCDs, 64 per chunk
    int bid = blockIdx.x;
    int swz = (bid & 7) * 64 + (bid >> 3);
    const int m0 = (swz >> 4) * BM;   // 32 m-blocks
    const int n0 = (swz & 15) * BN;   // 16 n-blocks

    // ---- staging addresses (pre-swizzled global source, linear LDS dest) ----
    const int l8 = lane >> 3;                 // 0..7  (row within 8-row chunk)
    const int lc = ((lane & 7) ^ l8) * 8;     // inverse-swizzled col (elems)
    const unsigned short* aS = A + (size_t)(m0 + wave * 16 + l8) * K_DIM + lc;
    const unsigned short* bS = B + (size_t)(n0 + wave * 16 + l8) * K_DIM + lc;
    char* const lds0 = smem;
    char* const lds1 = smem + BUF_BYTES;
    const int chunkoff = wave * 2048;         // 2 chunks x 1024B per wave

    auto stageA = [&](char* buf, int h, int kt) {
        const unsigned short* s0 = aS + (size_t)(h * 128) * K_DIM + kt;
        char* d0 = buf + h * HALF + chunkoff;
        __builtin_amdgcn_global_load_lds((glb_void_t*)s0,
            (lds_void_t*)(void*)d0, 16, 0, 0);
        __builtin_amdgcn_global_load_lds((glb_void_t*)(s0 + 8 * K_DIM),
            (lds_void_t*)(void*)(d0 + 1024), 16, 0, 0);
    };
    auto stageB = [&](char* buf, int h, int kt) {
        const unsigned short* s0 = bS + (size_t)(h * 128) * K_DIM + kt;
        char* d0 = buf + B_TILE + h * HALF + chunkoff;
        __builtin_amdgcn_global_load_lds((glb_void_t*)s0,
            (lds_void_t*)(void*)d0, 16, 0, 0);
        __builtin_amdgcn_global_load_lds((glb_void_t*)(s0 + 8 * K_DIM),
            (lds_void_t*)(void*)(d0 + 1024), 16, 0, 0);
    };

    // ---- fragment-read offsets (swizzled) ----
    const int swzc = (lr & 7) << 4;
    const int cx0 = (lk * 16) ^ swzc;         // kk=0 col bytes, swizzled
    const int cx1 = (64 + lk * 16) ^ swzc;    // kk=1
    const int arow = (wm * 64 + lr) * 128;
    const int brow = (wn * 32 + lr) * 128 + B_TILE;

    f32x4 acc[2][4][2][2] = {};   // [mh][im][nh][jn]
    bf16x8 afr[4][2];             // [im][kk]  (current mh)
    bf16x8 bfr[2][2][2];          // [nh][jn][kk]

    auto lda = [&](const char* cur, int mh) {
#pragma unroll
        for (int im = 0; im < 4; ++im) {
            const char* p = cur + arow + mh * HALF + im * 2048;
            afr[im][0] = *(const bf16x8*)(p + cx0);
            afr[im][1] = *(const bf16x8*)(p + cx1);
        }
    };
    auto ldb = [&](const char* cur, int nh) {
#pragma unroll
        for (int jn = 0; jn < 2; ++jn) {
            const char* p = cur + brow + nh * HALF + jn * 2048;
            bfr[nh][jn][0] = *(const bf16x8*)(p + cx0);
            bfr[nh][jn][1] = *(const bf16x8*)(p + cx1);
        }
    };

    // ---- prologue: stage tile0 (all 4 halves) + tile1 (Ah0,Bh0,Bh1) ----
    stageA(lds0, 0, 0);   // t0.Ah0
    stageB(lds0, 0, 0);   // t0.Bh0
    stageB(lds0, 1, 0);   // t0.Bh1
    stageA(lds0, 1, 0);   // t0.Ah1
    stageA(lds1, 0, BK);  // t1.Ah0
    stageB(lds1, 0, BK);  // t1.Bh0
    stageB(lds1, 1, BK);  // t1.Bh1
    asm volatile("s_waitcnt vmcnt(6)" ::: "memory");   // tile0 fully resident
    BARRIER();

    char* cur = lds0;
    char* nxt = lds1;
    for (int tt = 0; tt < NTILES; ++tt) {
        const int ktn = (tt + 1) * BK;
        const int kt2 = (tt + 2) * BK;

        // ---- phase 1: quadrant (mh0, nh0); stage (t+1).Ah1 -> nxt ----
        lda(cur, 0);
        ldb(cur, 0);
        if (tt < NTILES - 1) stageA(nxt, 1, ktn);
        BARRIER();
        MM_Q(0, 0);
        BARRIER();

        // ---- phase 2: quadrant (mh0, nh1); stage (t+2).Ah0 -> cur ----
        ldb(cur, 1);
        if (tt < NTILES - 2) stageA(cur, 0, kt2);
        BARRIER();
        MM_Q(0, 1);
        BARRIER();

        // ---- phase 3: quadrant (mh1, nh1); stage (t+2).Bh0 -> cur ----
        lda(cur, 1);
        if (tt < NTILES - 2) stageB(cur, 0, kt2);
        BARRIER();
        MM_Q(1, 1);
        BARRIER();

        // ---- phase 4: quadrant (mh1, nh0); stage (t+2).Bh1 -> cur ----
        if (tt < NTILES - 2) stageB(cur, 1, kt2);
        BARRIER();
        MM_Q(1, 0);
        if (tt < NTILES - 2) {
            asm volatile("s_waitcnt vmcnt(4)" ::: "memory");  // keep 2 half-tiles in flight
        } else {
            asm volatile("s_waitcnt vmcnt(0)" ::: "memory");  // drain for final tiles
        }
        BARRIER();

        char* tmp = cur; cur = nxt; nxt = tmp;
    }

    // ---- epilogue: scale/bias/clip, fp32 store ----
#pragma unroll
    for (int mh = 0; mh < 2; ++mh)
#pragma unroll
    for (int nh = 0; nh < 2; ++nh)
#pragma unroll
    for (int jn = 0; jn < 2; ++jn) {
        int gc = n0 + nh * 128 + wn * 32 + jn * 16 + lr;
        float sc = scale[gc];
        float bi = bias[gc];
#pragma unroll
        for (int im = 0; im < 4; ++im) {
            int gr = m0 + mh * 128 + wm * 64 + im * 16 + lk * 4;
#pragma unroll
            for (int v = 0; v < 4; ++v) {
                float val = acc[mh][im][nh][jn][v] * sc + bi;
                val = fminf(fmaxf(val, -100.0f), 100.0f);
                out[(size_t)(gr + v) * N_DIM + gc] = val;
            }
        }
    }
}

// ---------------- fallback: fused kernel (ws too small) ----------------
#define FBM 128
#define FBN 128
#define FBK 64

__global__ __launch_bounds__(256)
void ternary_mm_fused(const float* __restrict__ x,
                      const int* __restrict__ pw,
                      const float* __restrict__ scale,
                      const float* __restrict__ bias,
                      float* __restrict__ out)
{
    __shared__ unsigned char As[FBM * FBK * 2];
    __shared__ unsigned char Ws[FBN * FBK * 2];

    const int t    = threadIdx.x;
    const int lane = t & 63;
    const int wave = t >> 6;
    const int wr = wave >> 1;
    const int wc = wave & 1;
    const int lr = lane & 15;
    const int lk = lane >> 4;

    const int n0 = blockIdx.x * FBN;
    const int m0 = blockIdx.y * FBM;

    f32x4 acc[4][4];
#pragma unroll
    for (int m = 0; m < 4; ++m)
#pragma unroll
        for (int n = 0; n < 4; ++n)
            acc[m][n] = (f32x4){0.f, 0.f, 0.f, 0.f};

    for (int kt = 0; kt < K_DIM; kt += FBK) {
#pragma unroll
        for (int p = 0; p < 8; ++p) {
            int idx = p * 256 + t;
            int row = idx >> 4;
            int c4  = idx & 15;
            float4 v = *(const float4*)(x + (size_t)(m0 + row) * K_DIM + kt + c4 * 4);
            ushort4 o;
            o.x = f2bf(v.x); o.y = f2bf(v.y); o.z = f2bf(v.z); o.w = f2bf(v.w);
            int off = (row * 128 + c4 * 8) ^ ((row & 7) << 4);
            *(ushort4*)(As + off) = o;
        }
#pragma unroll
        for (int p = 0; p < 2; ++p) {
            int idx = p * 256 + t;
            int row = idx >> 2;
            int q   = idx & 3;
            int4 v = *(const int4*)(pw + (size_t)(n0 + row) * PW_COLS + (kt >> 2) + q * 4);
            int base = row * 128 + q * 32;
            int xr = (row & 7) << 4;
            int pv[4] = {v.x, v.y, v.z, v.w};
#pragma unroll
            for (int j = 0; j < 4; ++j) {
                ushort4 o;
                o.x = wlut( pv[j]       & 3);
                o.y = wlut((pv[j] >> 2) & 3);
                o.z = wlut((pv[j] >> 4) & 3);
                o.w = wlut((pv[j] >> 6) & 3);
                *(ushort4*)(Ws + ((base + j * 8) ^ xr)) = o;
            }
        }
        __syncthreads();

#pragma unroll
        for (int kk = 0; kk < 2; ++kk) {
            const int cb = kk * 64 + lk * 16;
            bf16x8 af[4], bw[4];
#pragma unroll
            for (int m = 0; m < 4; ++m) {
                int row = wr * 64 + m * 16 + lr;
                af[m] = *(const bf16x8*)(As + ((row * 128 + cb) ^ ((lr & 7) << 4)));
            }
#pragma unroll
            for (int n = 0; n < 4; ++n) {
                int row = wc * 64 + n * 16 + lr;
                bw[n] = *(const bf16x8*)(Ws + ((row * 128 + cb) ^ ((lr & 7) << 4)));
            }
#pragma unroll
            for (int m = 0; m < 4; ++m)
#pragma unroll
                for (int n = 0; n < 4; ++n)
                    acc[m][n] = __builtin_amdgcn_mfma_f32_16x16x32_bf16(
                        af[m], bw[n], acc[m][n], 0, 0, 0);
        }
        __syncthreads();
    }

#pragma unroll
    for (int n = 0; n < 4; ++n) {
        int gcol = n0 + wc * 64 + n * 16 + lr;
        float s = scale[gcol];
        float b = bias[gcol];
#pragma unroll
        for (int m = 0; m < 4; ++m) {
            int growb = m0 + wr * 64 + m * 16 + lk * 4;
#pragma unroll
            for (int r = 0; r < 4; ++r) {
                float v = acc[m][n][r] * s + b;
                v = fminf(fmaxf(v, -100.0f), 100.0f);
                out[(size_t)(growb + r) * N_DIM + gcol] = v;
            }
        }
    }
}

extern "C" void kernel_launch(void* const* d_in, const int* in_sizes, int n_in,
                              void* d_out, int out_size, void* d_ws, size_t ws_size,
                              hipStream_t stream) {
    const float* x     = (const float*)d_in[0];
    const int*   pw    = (const int*)d_in[1];
    const float* scale = (const float*)d_in[2];
    const float* bias  = (const float*)d_in[3];
    float* out = (float*)d_out;

    const size_t xb_bytes = (size_t)M_DIM * K_DIM * 2;
    const size_t wb_bytes = (size_t)N_DIM * K_DIM * 2;
    if (ws_size >= xb_bytes + wb_bytes) {
        unsigned short* xb = (unsigned short*)d_ws;
        unsigned short* wb = (unsigned short*)((char*)d_ws + xb_bytes);

        int n8 = (M_DIM * K_DIM) / 8;
        convert_x_kernel<<<2048, 256, 0, stream>>>(x, xb, n8);
        int n2 = (N_DIM * PW_COLS) / 2;
        unpack_w_kernel<<<2048, 256, 0, stream>>>(pw, wb, n2);

        (void)hipFuncSetAttribute(reinterpret_cast<const void*>(gemm_8phase),
                                  hipFuncAttributeMaxDynamicSharedMemorySize,
                                  2 * BUF_BYTES);
        dim3 grid((M_DIM / BM) * (N_DIM / BN));   // 512
        gemm_8phase<<<grid, GTHREADS, 2 * BUF_BYTES, stream>>>(xb, wb, scale, bias, out);
    } else {
        dim3 grid(N_DIM / FBN, M_DIM / FBM);
        ternary_mm_fused<<<grid, 256, 0, stream>>>(x, pw, scale, bias, out);
    }
}

// Round 5
// 248.635 us; speedup vs baseline: 1.7966x; 1.0503x over previous
//
#include <hip/hip_runtime.h>
#include <hip/hip_bf16.h>

#define K_DIM 4096
#define N_DIM 4096
#define M_DIM 8192
#define PW_COLS 1024  // K_DIM/4

typedef __attribute__((ext_vector_type(4))) float f32x4;
typedef __attribute__((ext_vector_type(8))) short bf16x8;
typedef __attribute__((address_space(3))) void lds_void_t;
typedef __attribute__((address_space(1))) const void glb_void_t;

__device__ __forceinline__ unsigned short f2bf(float f) {
    unsigned int u = __float_as_uint(f);
    u += 0x7FFF + ((u >> 16) & 1);   // round-to-nearest-even
    return (unsigned short)(u >> 16);
}

// ternary code {0,1,2,3} -> bf16 bits of {-1,0,1,2}
__device__ __forceinline__ unsigned short wlut(int tt) {
    return (unsigned short)(0x40003F800000BF80ULL >> (tt << 4));
}

// ---------------- pre-pass 1: x fp32 -> bf16 ----------------
__global__ __launch_bounds__(256)
void convert_x_kernel(const float* __restrict__ x, unsigned short* __restrict__ xb, int n8)
{
    int stride = gridDim.x * blockDim.x;
    for (int i = blockIdx.x * blockDim.x + threadIdx.x; i < n8; i += stride) {
        float4 v0 = *(const float4*)(x + (size_t)i * 8);
        float4 v1 = *(const float4*)(x + (size_t)i * 8 + 4);
        ushort4 o0, o1;
        o0.x = f2bf(v0.x); o0.y = f2bf(v0.y); o0.z = f2bf(v0.z); o0.w = f2bf(v0.w);
        o1.x = f2bf(v1.x); o1.y = f2bf(v1.y); o1.z = f2bf(v1.z); o1.w = f2bf(v1.w);
        *(ushort4*)(xb + (size_t)i * 8) = o0;
        *(ushort4*)(xb + (size_t)i * 8 + 4) = o1;
    }
}

// ---------------- pre-pass 2: pw -> bf16 W [N][K] ----------------
__global__ __launch_bounds__(256)
void unpack_w_kernel(const int* __restrict__ pw, unsigned short* __restrict__ wb, int n2)
{
    int stride = gridDim.x * blockDim.x;
    for (int i = blockIdx.x * blockDim.x + threadIdx.x; i < n2; i += stride) {
        int2 p = *(const int2*)(pw + (size_t)i * 2);
        ushort4 a, b;
        a.x = wlut( p.x       & 3);
        a.y = wlut((p.x >> 2) & 3);
        a.z = wlut((p.x >> 4) & 3);
        a.w = wlut((p.x >> 6) & 3);
        b.x = wlut( p.y       & 3);
        b.y = wlut((p.y >> 2) & 3);
        b.z = wlut((p.y >> 4) & 3);
        b.w = wlut((p.y >> 6) & 3);
        *(ushort4*)(wb + (size_t)i * 8) = a;
        *(ushort4*)(wb + (size_t)i * 8 + 4) = b;
    }
}

// ---------------- main GEMM: 256x256 tile, pipelined single-barrier regions ----------------
#define BM 256
#define BN 256
#define BK 64
#define GTHREADS 512
#define BUF_BYTES 65536   // A 32K + B 32K
#define B_TILE 32768
#define HALF 16384
#define NTILES 64         // K_DIM / BK

#define BARRIER() asm volatile("s_barrier" ::: "memory")
#define VMCNT(N)  asm volatile("s_waitcnt vmcnt(" #N ")" ::: "memory")

// MFMA quadrant: 16 MFMAs, kk-outer (8 independent per kk; acc dep distance 8)
#define MMQ(Aarr, Barr, MH, NH) do { \
    __builtin_amdgcn_s_setprio(1); \
    _Pragma("unroll") \
    for (int kk = 0; kk < 2; ++kk) { \
      _Pragma("unroll") \
      for (int im = 0; im < 4; ++im) { \
        _Pragma("unroll") \
        for (int jn = 0; jn < 2; ++jn) { \
          acc[MH][im][NH][jn] = __builtin_amdgcn_mfma_f32_16x16x32_bf16( \
              Aarr[im][kk], Barr[jn][kk], acc[MH][im][NH][jn], 0, 0, 0); \
        } \
      } \
    } \
    __builtin_amdgcn_s_setprio(0); \
} while (0)

__global__ __launch_bounds__(GTHREADS, 2)
void gemm_pipe(const unsigned short* __restrict__ A,   // [M][K] bf16
               const unsigned short* __restrict__ B,   // [N][K] bf16
               const float* __restrict__ scale,
               const float* __restrict__ bias,
               float* __restrict__ out)
{
    extern __shared__ __align__(16) char smem[];

    const int t    = threadIdx.x;
    const int lane = t & 63;
    const int wave = t >> 6;
    const int wm = wave >> 2;      // 0..1  (M group)
    const int wn = wave & 3;       // 0..3  (N group)
    const int lr = lane & 15;
    const int lk = lane >> 4;      // 0..3

    // bijective XCD swizzle: 512 blocks, 8 XCDs, 64 per chunk
    int bid = blockIdx.x;
    int swz = (bid & 7) * 64 + (bid >> 3);
    const int m0 = (swz >> 4) * BM;   // 32 m-blocks
    const int n0 = (swz & 15) * BN;   // 16 n-blocks

    // ---- staging addresses (pre-swizzled global source, linear LDS dest) ----
    const int l8 = lane >> 3;                 // 0..7  (row within 8-row chunk)
    const int lc = ((lane & 7) ^ l8) * 8;     // inverse-swizzled col (elems)
    const unsigned short* aS = A + (size_t)(m0 + wave * 16 + l8) * K_DIM + lc;
    const unsigned short* bS = B + (size_t)(n0 + wave * 16 + l8) * K_DIM + lc;
    char* const lds0 = smem;
    char* const lds1 = smem + BUF_BYTES;
    const int chunkoff = wave * 2048;         // 2 chunks x 1024B per wave

    auto stageA = [&](char* buf, int h, int kt) {
        const unsigned short* s0 = aS + (size_t)(h * 128) * K_DIM + kt;
        char* d0 = buf + h * HALF + chunkoff;
        __builtin_amdgcn_global_load_lds((glb_void_t*)s0,
            (lds_void_t*)(void*)d0, 16, 0, 0);
        __builtin_amdgcn_global_load_lds((glb_void_t*)(s0 + 8 * K_DIM),
            (lds_void_t*)(void*)(d0 + 1024), 16, 0, 0);
    };
    auto stageB = [&](char* buf, int h, int kt) {
        const unsigned short* s0 = bS + (size_t)(h * 128) * K_DIM + kt;
        char* d0 = buf + B_TILE + h * HALF + chunkoff;
        __builtin_amdgcn_global_load_lds((glb_void_t*)s0,
            (lds_void_t*)(void*)d0, 16, 0, 0);
        __builtin_amdgcn_global_load_lds((glb_void_t*)(s0 + 8 * K_DIM),
            (lds_void_t*)(void*)(d0 + 1024), 16, 0, 0);
    };

    // ---- fragment-read offsets (swizzled) ----
    const int swzc = (lr & 7) << 4;
    const int cx0 = (lk * 16) ^ swzc;         // kk=0 col bytes, swizzled
    const int cx1 = (64 + lk * 16) ^ swzc;    // kk=1
    const int arow = (wm * 64 + lr) * 128;
    const int brow = (wn * 32 + lr) * 128 + B_TILE;

    f32x4 acc[2][4][2][2] = {};   // [mh][im][nh][jn]
    bf16x8 a0[4][2], a1[4][2];    // A-half fragments [im][kk]
    bf16x8 b0[2][2], b1[2][2];    // B-half fragments [jn][kk]

    auto LDA = [&](bf16x8 (&dst)[4][2], const char* buf, int mh) {
#pragma unroll
        for (int im = 0; im < 4; ++im) {
            const char* p = buf + arow + mh * HALF + im * 2048;
            dst[im][0] = *(const bf16x8*)(p + cx0);
            dst[im][1] = *(const bf16x8*)(p + cx1);
        }
    };
    auto LDB = [&](bf16x8 (&dst)[2][2], const char* buf, int nh) {
#pragma unroll
        for (int jn = 0; jn < 2; ++jn) {
            const char* p = buf + brow + nh * HALF + jn * 2048;
            dst[jn][0] = *(const bf16x8*)(p + cx0);
            dst[jn][1] = *(const bf16x8*)(p + cx1);
        }
    };

    // ---- prologue: stage tile0 -> buf0, tile1 -> buf1 (16 loads) ----
    stageA(lds0, 0, 0);  stageB(lds0, 0, 0);
    stageB(lds0, 1, 0);  stageA(lds0, 1, 0);
    stageA(lds1, 0, BK); stageB(lds1, 0, BK);
    stageB(lds1, 1, BK); stageA(lds1, 1, BK);
    VMCNT(8);            // tile0 fully resident (tile1's 8 still in flight)
    BARRIER();
    // preload tile0's Q(0,0) fragments (plays the role of R3/R4 of tile -1)
    LDA(a0, lds0, 0);
    LDB(b0, lds0, 0);

    char* cur = lds0;
    char* nxt = lds1;
    for (int tt = 0; tt < NTILES; ++tt) {
        const int kt2 = (tt + 2) * BK;
        const bool st = (tt < NTILES - 2);
        const bool rd = (tt < NTILES - 1);

        // ---- R1: reads b1<-cur.Bh1 ; MFMA Q(0,0) ----
        LDB(b1, cur, 1);
        MMQ(a0, b0, 0, 0);
        BARRIER();

        // ---- R2: reads a1<-cur.Ah1 ; stage t+2.{Ah0,Bh0}->cur ; MFMA Q(0,1) ----
        LDA(a1, cur, 1);
        if (st) { stageA(cur, 0, kt2); stageB(cur, 0, kt2); }
        MMQ(a0, b1, 0, 1);
        // completes t+1.{Ah0,Bh0} (needed R3/R4). Tail: no new issues, so
        // outstanding==8 and vmcnt(8) would be a no-op -> drain to 4.
        if (st) { VMCNT(8); } else { VMCNT(4); }
        BARRIER();

        // ---- R3: reads a0<-nxt.Ah0 (next tile) ; stage t+2.Bh1->cur ; MFMA Q(1,1) ----
        if (rd) LDA(a0, nxt, 0);
        if (st) stageB(cur, 1, kt2);
        MMQ(a1, b1, 1, 1);
        BARRIER();

        // ---- R4: stage t+2.Ah1->cur ; MFMA Q(1,0) ; reads b0<-nxt.Bh0 ----
        if (st) stageA(cur, 1, kt2);
        MMQ(a1, b0, 1, 0);
        if (rd) LDB(b0, nxt, 0);
        // completes t+1.{Bh1,Ah1} (needed R1/R2 of t+1). Tail drain to 0.
        if (st) { VMCNT(8); } else { VMCNT(0); }
        BARRIER();

        char* tmp = cur; cur = nxt; nxt = tmp;
    }

    // ---- epilogue: scale/bias/clip, fp32 store ----
#pragma unroll
    for (int mh = 0; mh < 2; ++mh)
#pragma unroll
    for (int nh = 0; nh < 2; ++nh)
#pragma unroll
    for (int jn = 0; jn < 2; ++jn) {
        int gc = n0 + nh * 128 + wn * 32 + jn * 16 + lr;
        float sc = scale[gc];
        float bi = bias[gc];
#pragma unroll
        for (int im = 0; im < 4; ++im) {
            int gr = m0 + mh * 128 + wm * 64 + im * 16 + lk * 4;
#pragma unroll
            for (int v = 0; v < 4; ++v) {
                float val = acc[mh][im][nh][jn][v] * sc + bi;
                val = fminf(fmaxf(val, -100.0f), 100.0f);
                out[(size_t)(gr + v) * N_DIM + gc] = val;
            }
        }
    }
}

// ---------------- fallback: fused kernel (ws too small) ----------------
#define FBM 128
#define FBN 128
#define FBK 64

__global__ __launch_bounds__(256)
void ternary_mm_fused(const float* __restrict__ x,
                      const int* __restrict__ pw,
                      const float* __restrict__ scale,
                      const float* __restrict__ bias,
                      float* __restrict__ out)
{
    __shared__ unsigned char As[FBM * FBK * 2];
    __shared__ unsigned char Ws[FBN * FBK * 2];

    const int t    = threadIdx.x;
    const int lane = t & 63;
    const int wave = t >> 6;
    const int wr = wave >> 1;
    const int wc = wave & 1;
    const int lr = lane & 15;
    const int lk = lane >> 4;

    const int n0 = blockIdx.x * FBN;
    const int m0 = blockIdx.y * FBM;

    f32x4 acc[4][4];
#pragma unroll
    for (int m = 0; m < 4; ++m)
#pragma unroll
        for (int n = 0; n < 4; ++n)
            acc[m][n] = (f32x4){0.f, 0.f, 0.f, 0.f};

    for (int kt = 0; kt < K_DIM; kt += FBK) {
#pragma unroll
        for (int p = 0; p < 8; ++p) {
            int idx = p * 256 + t;
            int row = idx >> 4;
            int c4  = idx & 15;
            float4 v = *(const float4*)(x + (size_t)(m0 + row) * K_DIM + kt + c4 * 4);
            ushort4 o;
            o.x = f2bf(v.x); o.y = f2bf(v.y); o.z = f2bf(v.z); o.w = f2bf(v.w);
            int off = (row * 128 + c4 * 8) ^ ((row & 7) << 4);
            *(ushort4*)(As + off) = o;
        }
#pragma unroll
        for (int p = 0; p < 2; ++p) {
            int idx = p * 256 + t;
            int row = idx >> 2;
            int q   = idx & 3;
            int4 v = *(const int4*)(pw + (size_t)(n0 + row) * PW_COLS + (kt >> 2) + q * 4);
            int base = row * 128 + q * 32;
            int xr = (row & 7) << 4;
            int pv[4] = {v.x, v.y, v.z, v.w};
#pragma unroll
            for (int j = 0; j < 4; ++j) {
                ushort4 o;
                o.x = wlut( pv[j]       & 3);
                o.y = wlut((pv[j] >> 2) & 3);
                o.z = wlut((pv[j] >> 4) & 3);
                o.w = wlut((pv[j] >> 6) & 3);
                *(ushort4*)(Ws + ((base + j * 8) ^ xr)) = o;
            }
        }
        __syncthreads();

#pragma unroll
        for (int kk = 0; kk < 2; ++kk) {
            const int cb = kk * 64 + lk * 16;
            bf16x8 af[4], bw[4];
#pragma unroll
            for (int m = 0; m < 4; ++m) {
                int row = wr * 64 + m * 16 + lr;
                af[m] = *(const bf16x8*)(As + ((row * 128 + cb) ^ ((lr & 7) << 4)));
            }
#pragma unroll
            for (int n = 0; n < 4; ++n) {
                int row = wc * 64 + n * 16 + lr;
                bw[n] = *(const bf16x8*)(Ws + ((row * 128 + cb) ^ ((lr & 7) << 4)));
            }
#pragma unroll
            for (int m = 0; m < 4; ++m)
#pragma unroll
                for (int n = 0; n < 4; ++n)
                    acc[m][n] = __builtin_amdgcn_mfma_f32_16x16x32_bf16(
                        af[m], bw[n], acc[m][n], 0, 0, 0);
        }
        __syncthreads();
    }

#pragma unroll
    for (int n = 0; n < 4; ++n) {
        int gcol = n0 + wc * 64 + n * 16 + lr;
        float s = scale[gcol];
        float b = bias[gcol];
#pragma unroll
        for (int m = 0; m < 4; ++m) {
            int growb = m0 + wr * 64 + m * 16 + lk * 4;
#pragma unroll
            for (int r = 0; r < 4; ++r) {
                float v = acc[m][n][r] * s + b;
                v = fminf(fmaxf(v, -100.0f), 100.0f);
                out[(size_t)(growb + r) * N_DIM + gcol] = v;
            }
        }
    }
}

extern "C" void kernel_launch(void* const* d_in, const int* in_sizes, int n_in,
                              void* d_out, int out_size, void* d_ws, size_t ws_size,
                              hipStream_t stream) {
    const float* x     = (const float*)d_in[0];
    const int*   pw    = (const int*)d_in[1];
    const float* scale = (const float*)d_in[2];
    const float* bias  = (const float*)d_in[3];
    float* out = (float*)d_out;

    const size_t xb_bytes = (size_t)M_DIM * K_DIM * 2;
    const size_t wb_bytes = (size_t)N_DIM * K_DIM * 2;
    if (ws_size >= xb_bytes + wb_bytes) {
        unsigned short* xb = (unsigned short*)d_ws;
        unsigned short* wb = (unsigned short*)((char*)d_ws + xb_bytes);

        int n8 = (M_DIM * K_DIM) / 8;
        convert_x_kernel<<<2048, 256, 0, stream>>>(x, xb, n8);
        int n2 = (N_DIM * PW_COLS) / 2;
        unpack_w_kernel<<<2048, 256, 0, stream>>>(pw, wb, n2);

        (void)hipFuncSetAttribute(reinterpret_cast<const void*>(gemm_pipe),
                                  hipFuncAttributeMaxDynamicSharedMemorySize,
                                  2 * BUF_BYTES);
        dim3 grid((M_DIM / BM) * (N_DIM / BN));   // 512
        gemm_pipe<<<grid, GTHREADS, 2 * BUF_BYTES, stream>>>(xb, wb, scale, bias, out);
    } else {
        dim3 grid(N_DIM / FBN, M_DIM / FBM);
        ternary_mm_fused<<<grid, 256, 0, stream>>>(x, pw, scale, bias, out);
    }
}